// Round 1
// baseline (3453.590 us; speedup 1.0000x reference)
//
#include <hip/hip_runtime.h>
#include <hip/hip_bf16.h>
#include <cstdint>
#include <cstddef>

#define B_ALL 256
#define T_LEN 512
#define D_INP 64
#define HD    128
#define G4    512            // 4*H
#define NC    12
#define BCH   128            // batch per chunk
#define ROWS  (BCH * T_LEN)  // 65536 rows per chunk

// ---------- helpers ----------
__device__ __forceinline__ float bf2f(unsigned short u) {
    union { unsigned int i; float f; } v; v.i = ((unsigned int)u) << 16; return v.f;
}
__device__ __forceinline__ unsigned short f2bf(float f) {
    union { float f; unsigned int i; } v; v.f = f;
    unsigned int r = v.i + 0x7FFFu + ((v.i >> 16) & 1u);  // round-nearest-even
    return (unsigned short)(r >> 16);
}
__device__ __forceinline__ float sigf(float x) { return 1.0f / (1.0f + __expf(-x)); }
__device__ __forceinline__ float tanh_f(float x) {
    float xx = fminf(15.0f, fmaxf(-15.0f, x));
    float e = __expf(2.0f * xx);
    return (e - 1.0f) / (e + 1.0f);
}

__device__ __forceinline__ float4 loadA4(const float* p) { return *(const float4*)p; }
__device__ __forceinline__ float4 loadA4(const unsigned short* p) {
    ushort4 u = *(const ushort4*)p;  // 8B aligned
    return make_float4(bf2f(u.x), bf2f(u.y), bf2f(u.z), bf2f(u.w));
}

// LDS-only barrier: drains lgkmcnt (ds ops) but leaves global loads/stores in
// flight (no vmcnt(0) drain, unlike __syncthreads). All cross-thread traffic in
// lstm_rec goes through LDS, so this is sufficient for correctness.
#define LDS_BARRIER() asm volatile("s_waitcnt lgkmcnt(0)\n\ts_barrier" ::: "memory")

// ---------- gates GEMM: out[r][c] = bias[c] + sum_k A[r][k] * W[c][k] ----------
// out is bf16 [rows][1024]; c = dir*512 + g. Tile 128x128, 256 threads, 8x8/thread.
// Skips blocks whose entire 128-row span has t >= len[b] (outputs never consumed).
template <typename TA>
__global__ __launch_bounds__(256)
void gates_gemm(const TA* __restrict__ A, const float* __restrict__ W,
                const float* __restrict__ bias, const int* __restrict__ lens,
                unsigned short* __restrict__ out, int K)
{
    int row0 = blockIdx.x * 128;
    int col0 = blockIdx.y * 128;
    int bl = row0 >> 9;            // T_LEN = 512 rows per batch element
    int t0 = row0 & (T_LEN - 1);
    if (t0 >= lens[bl]) return;    // whole tile masked -> never read downstream

    __shared__ float As[32][130];  // [k][row], stride 130: conflict-light, 8B aligned
    __shared__ float Bs[32][130];

    int tid = threadIdx.x;
    int tx = tid & 15;             // col group
    int ty = tid >> 4;             // row group
    int lr = tid >> 3;             // 0..31 staging row
    int lk = (tid & 7) * 4;        // 0,4,...,28 staging k

    float acc[8][8];
#pragma unroll
    for (int i = 0; i < 8; ++i)
#pragma unroll
        for (int j = 0; j < 8; ++j) acc[i][j] = 0.0f;

    for (int kt = 0; kt < K; kt += 32) {
#pragma unroll
        for (int rr = 0; rr < 128; rr += 32) {
            int r = rr + lr;
            float4 v = loadA4(A + (size_t)(row0 + r) * K + kt + lk);
            As[lk + 0][r] = v.x; As[lk + 1][r] = v.y;
            As[lk + 2][r] = v.z; As[lk + 3][r] = v.w;
        }
#pragma unroll
        for (int rr = 0; rr < 128; rr += 32) {
            int c = rr + lr;
            float4 v = *(const float4*)(W + (size_t)(col0 + c) * K + kt + lk);
            Bs[lk + 0][c] = v.x; Bs[lk + 1][c] = v.y;
            Bs[lk + 2][c] = v.z; Bs[lk + 3][c] = v.w;
        }
        __syncthreads();
#pragma unroll 8
        for (int kk = 0; kk < 32; ++kk) {
            float a[8], b[8];
#pragma unroll
            for (int q = 0; q < 4; ++q) {
                float2 t = *(const float2*)&As[kk][ty * 8 + 2 * q];
                a[2 * q] = t.x; a[2 * q + 1] = t.y;
                float2 u = *(const float2*)&Bs[kk][tx * 8 + 2 * q];
                b[2 * q] = u.x; b[2 * q + 1] = u.y;
            }
#pragma unroll
            for (int i = 0; i < 8; ++i)
#pragma unroll
                for (int j = 0; j < 8; ++j) acc[i][j] += a[i] * b[j];
        }
        __syncthreads();
    }

    float bj[8];
#pragma unroll
    for (int j = 0; j < 8; ++j) bj[j] = bias[col0 + tx * 8 + j];
#pragma unroll
    for (int i = 0; i < 8; ++i) {
        size_t base = (size_t)(row0 + ty * 8 + i) * 1024 + col0 + tx * 8;
        ushort4 p0, p1;
        p0.x = f2bf(acc[i][0] + bj[0]); p0.y = f2bf(acc[i][1] + bj[1]);
        p0.z = f2bf(acc[i][2] + bj[2]); p0.w = f2bf(acc[i][3] + bj[3]);
        p1.x = f2bf(acc[i][4] + bj[4]); p1.y = f2bf(acc[i][5] + bj[5]);
        p1.z = f2bf(acc[i][6] + bj[6]); p1.w = f2bf(acc[i][7] + bj[7]);
        *(ushort4*)&out[base] = p0;
        *(ushort4*)&out[base + 4] = p1;
    }
}

// ---------- LSTM recurrence: one block per (dir, batch-element) ----------
// 512 threads; thread j owns gate row j with Whh[j][0:128] in registers.
// h broadcast through LDS each step; loop stops at len[b] (mask => freeze + zero).
// Per-step latency optimizations (R1):
//  - next step's xg gate value is prefetched at loop top (one u16/thread); it is
//    consumed only in the NEXT iteration, so a full step (~1500+ cy) of compute
//    covers the ~500-900 cy HBM/L2 latency.
//  - barriers are lgkmcnt-only (LDS_BARRIER), so the prefetch load and the hs
//    store are never vmcnt-drained (unlike __syncthreads, which waits vmcnt(0)).
__global__ __launch_bounds__(512)
void lstm_rec(const unsigned short* __restrict__ xg,   // [ROWS][1024]
              const float* __restrict__ Whh,           // [2][512][128]
              const int* __restrict__ lens,            // chunk-offset
              unsigned short* __restrict__ hs,         // [ROWS][256] or null
              float* __restrict__ hTf, float* __restrict__ hTb,
              int bOff)
{
    int dir = blockIdx.x >> 7;   // 128 batch per chunk
    int bl  = blockIdx.x & 127;
    int L   = lens[bl];
    int j   = threadIdx.x;

    __shared__ float h_s[HD];
    __shared__ float g_s[G4];

    float w[HD];
    const float* wrow = Whh + ((size_t)dir * G4 + j) * HD;
#pragma unroll
    for (int k = 0; k < HD; k += 4) {
        float4 v = *(const float4*)(wrow + k);
        w[k] = v.x; w[k + 1] = v.y; w[k + 2] = v.z; w[k + 3] = v.w;
    }

    if (j < HD) h_s[j] = 0.0f;
    float c = 0.0f;
    float hkeep = 0.0f;
    __syncthreads();

    // gate stream for this thread: row tt is xgj[tt*1024]
    const unsigned short* xgj = xg + (size_t)bl * T_LEN * 1024 + (size_t)dir * G4 + j;
    int tt   = dir ? (L - 1) : 0;    // forward: 0,1,..  backward: L-1,L-2,..
    int step = dir ? -1 : 1;
    unsigned short gu = xgj[(size_t)tt * 1024];   // step-0 gate

    for (int t = 0; t < L; ++t) {
        // prefetch next step's gate (clamped to a valid row on the last step)
        int ttn = (t + 1 < L) ? (tt + step) : tt;
        unsigned short gun = xgj[(size_t)ttn * 1024];

        float g = bf2f(gu);
#pragma unroll
        for (int k = 0; k < HD; k += 4) {
            float4 h4 = *(const float4*)&h_s[k];   // wave-uniform broadcast read
            g += w[k] * h4.x + w[k + 1] * h4.y + w[k + 2] * h4.z + w[k + 3] * h4.w;
        }
        g_s[j] = g;
        LDS_BARRIER();
        if (j < HD) {
            float ig = sigf(g_s[j]);
            float fg = sigf(g_s[j + 128]);
            float gg = tanh_f(g_s[j + 256]);
            float og = sigf(g_s[j + 384]);
            c = fg * c + ig * gg;
            float hn = og * tanh_f(c);
            h_s[j] = hn;
            hkeep = hn;
            if (hs) hs[(size_t)(bl * T_LEN + tt) * 256 + dir * HD + j] = f2bf(hn);
        }
        LDS_BARRIER();
        gu = gun;
        tt += step;
    }
    if (hTf && j < HD) {
        (dir ? hTb : hTf)[(size_t)(bOff + bl) * HD + j] = hkeep;
    }
}

// ---------- final FC + log_softmax: h = [hT_b, hT_f] ----------
__global__ __launch_bounds__(256)
void fc_lsm(const float* __restrict__ hTf, const float* __restrict__ hTb,
            const float* __restrict__ Wfc, const float* __restrict__ bfc,
            float* __restrict__ out)
{
    int b = threadIdx.x;
    const float* hb = hTb + (size_t)b * HD;
    const float* hf = hTf + (size_t)b * HD;
    float l[NC];
#pragma unroll
    for (int cc = 0; cc < NC; ++cc) {
        const float* wr = Wfc + cc * 256;
        float acc = bfc[cc];
        for (int k = 0; k < HD; k += 4) {
            acc += hb[k] * wr[k] + hb[k + 1] * wr[k + 1]
                 + hb[k + 2] * wr[k + 2] + hb[k + 3] * wr[k + 3];
            acc += hf[k] * wr[128 + k] + hf[k + 1] * wr[128 + k + 1]
                 + hf[k + 2] * wr[128 + k + 2] + hf[k + 3] * wr[128 + k + 3];
        }
        l[cc] = acc;
    }
    float m = l[0];
#pragma unroll
    for (int cc = 1; cc < NC; ++cc) m = fmaxf(m, l[cc]);
    float s = 0.0f;
#pragma unroll
    for (int cc = 0; cc < NC; ++cc) s += __expf(l[cc] - m);
    float lg = m + logf(s);
#pragma unroll
    for (int cc = 0; cc < NC; ++cc) out[(size_t)b * NC + cc] = l[cc] - lg;
}

extern "C" void kernel_launch(void* const* d_in, const int* in_sizes, int n_in,
                              void* d_out, int out_size, void* d_ws, size_t ws_size,
                              hipStream_t stream)
{
    const float* X    = (const float*)d_in[0];
    const int*   len  = (const int*)d_in[1];
    const float* Wih0 = (const float*)d_in[2];   // (2,512,64)  -> (1024,64)
    const float* Whh0 = (const float*)d_in[3];   // (2,512,128)
    const float* b0   = (const float*)d_in[4];   // (2,512) -> (1024)
    const float* Wih1 = (const float*)d_in[5];   // (2,512,256) -> (1024,256)
    const float* Whh1 = (const float*)d_in[6];
    const float* b1   = (const float*)d_in[7];
    const float* Wfc  = (const float*)d_in[8];   // (12,256)
    const float* bfc  = (const float*)d_in[9];   // (12)
    float* out = (float*)d_out;

    char* ws = (char*)d_ws;
    unsigned short* xg = (unsigned short*)ws;                              // ROWS*1024 bf16
    unsigned short* h1 = (unsigned short*)(ws + (size_t)ROWS * 1024 * 2);  // ROWS*256 bf16
    float* hTf = (float*)(ws + (size_t)ROWS * 1024 * 2 + (size_t)ROWS * 256 * 2);
    float* hTb = hTf + (size_t)B_ALL * HD;

    dim3 blk(256);
    for (int ch = 0; ch < 2; ++ch) {
        const int* lc = len + ch * BCH;
        const float* Xc = X + (size_t)ch * BCH * T_LEN * D_INP;

        gates_gemm<float><<<dim3(ROWS / 128, 1024 / 128), blk, 0, stream>>>(
            Xc, Wih0, b0, lc, xg, D_INP);
        lstm_rec<<<2 * BCH, 512, 0, stream>>>(xg, Whh0, lc, h1, nullptr, nullptr, 0);
        gates_gemm<unsigned short><<<dim3(ROWS / 128, 1024 / 128), blk, 0, stream>>>(
            h1, Wih1, b1, lc, xg, 2 * HD);
        lstm_rec<<<2 * BCH, 512, 0, stream>>>(xg, Whh1, lc, nullptr, hTf, hTb, ch * BCH);
    }
    fc_lsm<<<1, 256, 0, stream>>>(hTf, hTb, Wfc, bfc, out);
}

// Round 2
// 3138.172 us; speedup vs baseline: 1.1005x; 1.1005x over previous
//
#include <hip/hip_runtime.h>
#include <hip/hip_bf16.h>
#include <cstdint>
#include <cstddef>

#define B_ALL 256
#define T_LEN 512
#define D_INP 64
#define HD    128
#define G4    512            // 4*H
#define NC    12
#define BCH   128            // batch per chunk
#define ROWS  (BCH * T_LEN)  // 65536 rows per chunk

// ---------- helpers ----------
__device__ __forceinline__ float bf2f(unsigned short u) {
    union { unsigned int i; float f; } v; v.i = ((unsigned int)u) << 16; return v.f;
}
__device__ __forceinline__ unsigned short f2bf(float f) {
    union { float f; unsigned int i; } v; v.f = f;
    unsigned int r = v.i + 0x7FFFu + ((v.i >> 16) & 1u);  // round-nearest-even
    return (unsigned short)(r >> 16);
}
__device__ __forceinline__ float sigf(float x) { return 1.0f / (1.0f + __expf(-x)); }
__device__ __forceinline__ float tanh_f(float x) {
    float xx = fminf(15.0f, fmaxf(-15.0f, x));
    float e = __expf(2.0f * xx);
    return (e - 1.0f) / (e + 1.0f);
}

__device__ __forceinline__ float4 loadA4(const float* p) { return *(const float4*)p; }
__device__ __forceinline__ float4 loadA4(const unsigned short* p) {
    ushort4 u = *(const ushort4*)p;  // 8B aligned
    return make_float4(bf2f(u.x), bf2f(u.y), bf2f(u.z), bf2f(u.w));
}

// LDS-only barrier: drains lgkmcnt (ds ops) but leaves global loads/stores in
// flight (no vmcnt(0) drain, unlike __syncthreads). All cross-thread traffic in
// lstm_rec goes through LDS, so this is sufficient for correctness.
#define LDS_BARRIER() asm volatile("s_waitcnt lgkmcnt(0)\n\ts_barrier" ::: "memory")

// ---------- gates GEMM: out[r][c] = bias[c] + sum_k A[r][k] * W[c][k] ----------
// out is bf16 [rows][1024]; c = dir*512 + g. Tile 128x128, 256 threads, 8x8/thread.
// Skips blocks whose entire 128-row span has t >= len[b] (outputs never consumed).
template <typename TA>
__global__ __launch_bounds__(256)
void gates_gemm(const TA* __restrict__ A, const float* __restrict__ W,
                const float* __restrict__ bias, const int* __restrict__ lens,
                unsigned short* __restrict__ out, int K)
{
    int row0 = blockIdx.x * 128;
    int col0 = blockIdx.y * 128;
    int bl = row0 >> 9;            // T_LEN = 512 rows per batch element
    int t0 = row0 & (T_LEN - 1);
    if (t0 >= lens[bl]) return;    // whole tile masked -> never read downstream

    __shared__ float As[32][130];  // [k][row], stride 130: conflict-light, 8B aligned
    __shared__ float Bs[32][130];

    int tid = threadIdx.x;
    int tx = tid & 15;             // col group
    int ty = tid >> 4;             // row group
    int lr = tid >> 3;             // 0..31 staging row
    int lk = (tid & 7) * 4;        // 0,4,...,28 staging k

    float acc[8][8];
#pragma unroll
    for (int i = 0; i < 8; ++i)
#pragma unroll
        for (int j = 0; j < 8; ++j) acc[i][j] = 0.0f;

    for (int kt = 0; kt < K; kt += 32) {
#pragma unroll
        for (int rr = 0; rr < 128; rr += 32) {
            int r = rr + lr;
            float4 v = loadA4(A + (size_t)(row0 + r) * K + kt + lk);
            As[lk + 0][r] = v.x; As[lk + 1][r] = v.y;
            As[lk + 2][r] = v.z; As[lk + 3][r] = v.w;
        }
#pragma unroll
        for (int rr = 0; rr < 128; rr += 32) {
            int c = rr + lr;
            float4 v = *(const float4*)(W + (size_t)(col0 + c) * K + kt + lk);
            Bs[lk + 0][c] = v.x; Bs[lk + 1][c] = v.y;
            Bs[lk + 2][c] = v.z; Bs[lk + 3][c] = v.w;
        }
        __syncthreads();
#pragma unroll 8
        for (int kk = 0; kk < 32; ++kk) {
            float a[8], b[8];
#pragma unroll
            for (int q = 0; q < 4; ++q) {
                float2 t = *(const float2*)&As[kk][ty * 8 + 2 * q];
                a[2 * q] = t.x; a[2 * q + 1] = t.y;
                float2 u = *(const float2*)&Bs[kk][tx * 8 + 2 * q];
                b[2 * q] = u.x; b[2 * q + 1] = u.y;
            }
#pragma unroll
            for (int i = 0; i < 8; ++i)
#pragma unroll
                for (int j = 0; j < 8; ++j) acc[i][j] += a[i] * b[j];
        }
        __syncthreads();
    }

    float bj[8];
#pragma unroll
    for (int j = 0; j < 8; ++j) bj[j] = bias[col0 + tx * 8 + j];
#pragma unroll
    for (int i = 0; i < 8; ++i) {
        size_t base = (size_t)(row0 + ty * 8 + i) * 1024 + col0 + tx * 8;
        ushort4 p0, p1;
        p0.x = f2bf(acc[i][0] + bj[0]); p0.y = f2bf(acc[i][1] + bj[1]);
        p0.z = f2bf(acc[i][2] + bj[2]); p0.w = f2bf(acc[i][3] + bj[3]);
        p1.x = f2bf(acc[i][4] + bj[4]); p1.y = f2bf(acc[i][5] + bj[5]);
        p1.z = f2bf(acc[i][6] + bj[6]); p1.w = f2bf(acc[i][7] + bj[7]);
        *(ushort4*)&out[base] = p0;
        *(ushort4*)&out[base + 4] = p1;
    }
}

// ---------- LSTM recurrence: one block per (dir, batch-element) ----------
// R2 re-partition: tid = ks*128 + rr. Thread (ks, rr) computes partial dot
// products for its output rr's FOUR gate rows (rr, rr+128, rr+256, rr+384)
// over k-quarter [32*ks, 32*ks+32). Benefits vs one-gate-per-thread:
//  - 4 independent 32-deep FMA chains instead of one 128-deep chain
//    (chain latency 512cy -> ~128cy per step)
//  - each wave reads only 32 h values (8 x ds_read_b128 broadcast, ks is
//    wave-uniform) instead of 128 (32 x b128): LDS pipe pressure /4.
// Partials reduced via gp[4][512] in LDS (conflict-free: consecutive lanes ->
// consecutive addresses on both write and read sides).
__global__ __launch_bounds__(512)
void lstm_rec(const unsigned short* __restrict__ xg,   // [ROWS][1024]
              const float* __restrict__ Whh,           // [2][512][128]
              const int* __restrict__ lens,            // chunk-offset
              unsigned short* __restrict__ hs,         // [ROWS][256] or null
              float* __restrict__ hTf, float* __restrict__ hTb,
              int bOff)
{
    int dir = blockIdx.x >> 7;   // 128 batch per chunk
    int bl  = blockIdx.x & 127;
    int L   = lens[bl];
    int tid = threadIdx.x;
    int ks  = tid >> 7;          // k-quarter 0..3 (wave-uniform)
    int rr  = tid & 127;         // output index 0..127

    __shared__ float h_s[HD];
    __shared__ float gp[4][G4];  // [ks][gate_row] partial sums

    // w[g][kk] = Whh[dir][g*128 + rr][ks*32 + kk]
    float w[4][32];
#pragma unroll
    for (int g = 0; g < 4; ++g) {
        const float* wrow = Whh + ((size_t)dir * G4 + g * HD + rr) * HD + ks * 32;
#pragma unroll
        for (int k = 0; k < 32; k += 4) {
            float4 v = *(const float4*)(wrow + k);
            w[g][k] = v.x; w[g][k + 1] = v.y; w[g][k + 2] = v.z; w[g][k + 3] = v.w;
        }
    }

    if (tid < HD) h_s[tid] = 0.0f;
    float c = 0.0f, hkeep = 0.0f;
    __syncthreads();

    const unsigned short* xgb = xg + (size_t)bl * T_LEN * 1024 + (size_t)dir * G4;
    int tt   = dir ? (L - 1) : 0;
    int step = dir ? -1 : 1;

    // nonlinearity threads preload their 4 gate biases for step 0
    float xv0 = 0.f, xv1 = 0.f, xv2 = 0.f, xv3 = 0.f;
    if (tid < HD) {
        const unsigned short* p = xgb + (size_t)tt * 1024;
        xv0 = bf2f(p[tid]);       xv1 = bf2f(p[tid + 128]);
        xv2 = bf2f(p[tid + 256]); xv3 = bf2f(p[tid + 384]);
    }

    for (int t = 0; t < L; ++t) {
        // ---- dot-product phase: all 8 waves ----
        float a0 = 0.f, a1 = 0.f, a2 = 0.f, a3 = 0.f;
        const float* hq = &h_s[ks * 32];
#pragma unroll
        for (int k = 0; k < 32; k += 4) {
            float4 h4 = *(const float4*)(hq + k);   // wave-uniform broadcast
            a0 += w[0][k] * h4.x + w[0][k+1] * h4.y + w[0][k+2] * h4.z + w[0][k+3] * h4.w;
            a1 += w[1][k] * h4.x + w[1][k+1] * h4.y + w[1][k+2] * h4.z + w[1][k+3] * h4.w;
            a2 += w[2][k] * h4.x + w[2][k+1] * h4.y + w[2][k+2] * h4.z + w[2][k+3] * h4.w;
            a3 += w[3][k] * h4.x + w[3][k+1] * h4.y + w[3][k+2] * h4.z + w[3][k+3] * h4.w;
        }
        gp[ks][rr]       = a0;
        gp[ks][rr + 128] = a1;
        gp[ks][rr + 256] = a2;
        gp[ks][rr + 384] = a3;
        LDS_BARRIER();

        // ---- reduce + nonlinearity: waves 0-1 ----
        if (tid < HD) {
            float gi = xv0 + ((gp[0][tid]       + gp[1][tid])       + (gp[2][tid]       + gp[3][tid]));
            float gf = xv1 + ((gp[0][tid + 128] + gp[1][tid + 128]) + (gp[2][tid + 128] + gp[3][tid + 128]));
            float gg = xv2 + ((gp[0][tid + 256] + gp[1][tid + 256]) + (gp[2][tid + 256] + gp[3][tid + 256]));
            float go = xv3 + ((gp[0][tid + 384] + gp[1][tid + 384]) + (gp[2][tid + 384] + gp[3][tid + 384]));

            // prefetch next step's biases (covered by barrier + next dot phase)
            int ttn = (t + 1 < L) ? (tt + step) : tt;
            const unsigned short* p = xgb + (size_t)ttn * 1024;
            xv0 = bf2f(p[tid]);       xv1 = bf2f(p[tid + 128]);
            xv2 = bf2f(p[tid + 256]); xv3 = bf2f(p[tid + 384]);

            float ig = sigf(gi);
            float fg = sigf(gf);
            float G  = tanh_f(gg);
            float og = sigf(go);
            c = fg * c + ig * G;
            float hn = og * tanh_f(c);
            h_s[tid] = hn;
            hkeep = hn;
            if (hs) hs[(size_t)(bl * T_LEN + tt) * 256 + dir * HD + tid] = f2bf(hn);
        }
        LDS_BARRIER();
        tt += step;
    }
    if (hTf && tid < HD) {
        (dir ? hTb : hTf)[(size_t)(bOff + bl) * HD + tid] = hkeep;
    }
}

// ---------- final FC + log_softmax: h = [hT_b, hT_f] ----------
__global__ __launch_bounds__(256)
void fc_lsm(const float* __restrict__ hTf, const float* __restrict__ hTb,
            const float* __restrict__ Wfc, const float* __restrict__ bfc,
            float* __restrict__ out)
{
    int b = threadIdx.x;
    const float* hb = hTb + (size_t)b * HD;
    const float* hf = hTf + (size_t)b * HD;
    float l[NC];
#pragma unroll
    for (int cc = 0; cc < NC; ++cc) {
        const float* wr = Wfc + cc * 256;
        float acc = bfc[cc];
        for (int k = 0; k < HD; k += 4) {
            acc += hb[k] * wr[k] + hb[k + 1] * wr[k + 1]
                 + hb[k + 2] * wr[k + 2] + hb[k + 3] * wr[k + 3];
            acc += hf[k] * wr[128 + k] + hf[k + 1] * wr[128 + k + 1]
                 + hf[k + 2] * wr[128 + k + 2] + hf[k + 3] * wr[128 + k + 3];
        }
        l[cc] = acc;
    }
    float m = l[0];
#pragma unroll
    for (int cc = 1; cc < NC; ++cc) m = fmaxf(m, l[cc]);
    float s = 0.0f;
#pragma unroll
    for (int cc = 0; cc < NC; ++cc) s += __expf(l[cc] - m);
    float lg = m + logf(s);
#pragma unroll
    for (int cc = 0; cc < NC; ++cc) out[(size_t)b * NC + cc] = l[cc] - lg;
}

extern "C" void kernel_launch(void* const* d_in, const int* in_sizes, int n_in,
                              void* d_out, int out_size, void* d_ws, size_t ws_size,
                              hipStream_t stream)
{
    const float* X    = (const float*)d_in[0];
    const int*   len  = (const int*)d_in[1];
    const float* Wih0 = (const float*)d_in[2];   // (2,512,64)  -> (1024,64)
    const float* Whh0 = (const float*)d_in[3];   // (2,512,128)
    const float* b0   = (const float*)d_in[4];   // (2,512) -> (1024)
    const float* Wih1 = (const float*)d_in[5];   // (2,512,256) -> (1024,256)
    const float* Whh1 = (const float*)d_in[6];
    const float* b1   = (const float*)d_in[7];
    const float* Wfc  = (const float*)d_in[8];   // (12,256)
    const float* bfc  = (const float*)d_in[9];   // (12)
    float* out = (float*)d_out;

    char* ws = (char*)d_ws;
    unsigned short* xg = (unsigned short*)ws;                              // ROWS*1024 bf16
    unsigned short* h1 = (unsigned short*)(ws + (size_t)ROWS * 1024 * 2);  // ROWS*256 bf16
    float* hTf = (float*)(ws + (size_t)ROWS * 1024 * 2 + (size_t)ROWS * 256 * 2);
    float* hTb = hTf + (size_t)B_ALL * HD;

    dim3 blk(256);
    for (int ch = 0; ch < 2; ++ch) {
        const int* lc = len + ch * BCH;
        const float* Xc = X + (size_t)ch * BCH * T_LEN * D_INP;

        gates_gemm<float><<<dim3(ROWS / 128, 1024 / 128), blk, 0, stream>>>(
            Xc, Wih0, b0, lc, xg, D_INP);
        lstm_rec<<<2 * BCH, 512, 0, stream>>>(xg, Whh0, lc, h1, nullptr, nullptr, 0);
        gates_gemm<unsigned short><<<dim3(ROWS / 128, 1024 / 128), blk, 0, stream>>>(
            h1, Wih1, b1, lc, xg, 2 * HD);
        lstm_rec<<<2 * BCH, 512, 0, stream>>>(xg, Whh1, lc, nullptr, hTf, hTb, ch * BCH);
    }
    fc_lsm<<<1, 256, 0, stream>>>(hTf, hTb, Wfc, bfc, out);
}

// Round 3
// 2400.024 us; speedup vs baseline: 1.4390x; 1.3076x over previous
//
#include <hip/hip_runtime.h>
#include <hip/hip_bf16.h>
#include <cstdint>
#include <cstddef>
#include <type_traits>

#define B_ALL 256
#define T_LEN 512
#define D_INP 64
#define HD    128
#define G4    512            // 4*H
#define NC    12
#define BCH   128            // batch per chunk
#define ROWS  (BCH * T_LEN)  // 65536 rows per chunk

// ---------- helpers ----------
__device__ __forceinline__ float bf2f(unsigned short u) {
    union { unsigned int i; float f; } v; v.i = ((unsigned int)u) << 16; return v.f;
}
__device__ __forceinline__ unsigned short f2bf(float f) {
    union { float f; unsigned int i; } v; v.f = f;
    unsigned int r = v.i + 0x7FFFu + ((v.i >> 16) & 1u);  // round-nearest-even
    return (unsigned short)(r >> 16);
}
__device__ __forceinline__ float sigf(float x) { return 1.0f / (1.0f + __expf(-x)); }
__device__ __forceinline__ float tanh_f(float x) {
    float xx = fminf(15.0f, fmaxf(-15.0f, x));
    float e = __expf(2.0f * xx);
    return (e - 1.0f) / (e + 1.0f);
}

// LDS-only barrier (rec): drains lgkmcnt but not vmcnt.
#define LDS_BARRIER() asm volatile("s_waitcnt lgkmcnt(0)\n\ts_barrier" ::: "memory")

using bf16x8 = __attribute__((ext_vector_type(8))) short;
using f32x4  = __attribute__((ext_vector_type(4))) float;

// XOR swizzle for [R][32] bf16 LDS tiles (64B rows). Toggles byte bits 4-5
// within each row -> frag-read lanes (stride 64B) spread over 4 bank groups
// instead of 1. Bijective (XOR only touches intra-row bits since kb < 64).
__device__ __forceinline__ int swz(int r, int kb) {
    return (r * 64 + kb) ^ ((r & 3) << 4);
}

// ---------- W split: fp32 -> hi/lo bf16 pair (hi+lo ~ fp32 exact) ----------
__global__ __launch_bounds__(256)
void split_w(const float* __restrict__ w, unsigned short* __restrict__ hi,
             unsigned short* __restrict__ lo, int n)
{
    int i = blockIdx.x * 256 + threadIdx.x;
    if (i < n) {
        float f = w[i];
        unsigned short h = f2bf(f);
        hi[i] = h;
        lo[i] = f2bf(f - bf2f(h));
    }
}

// ---------- gates GEMM (MFMA, split-precision bf16) ----------
// out[r][c] = bias[c] + sum_k A[r][k] * W[c][k], out bf16 [rows][1024].
// Tile 128x128, 256 threads = 4 waves in 2x2, each wave 64x64 via 4x4
// 16x16x32 frags. acc += Ahi*Whi + Ahi*Wlo (+ Alo*Whi when A is fp32).
// Error vs fp32: ~2^-17 relative (alo*blo term dropped).
// Skips blocks whose whole 128-row span has t >= len[b].
template <int TERMS, typename TA>
__global__ __launch_bounds__(256)
void gates_gemm_mfma(const TA* __restrict__ A,
                     const unsigned short* __restrict__ Whi_g,
                     const unsigned short* __restrict__ Wlo_g,
                     const float* __restrict__ bias,
                     const int* __restrict__ lens,
                     unsigned short* __restrict__ out, int K)
{
    int row0 = blockIdx.x * 128;
    int col0 = blockIdx.y * 128;
    int bl = row0 >> 9;
    int t0 = row0 & (T_LEN - 1);
    if (t0 >= lens[bl]) return;

    __shared__ __align__(16) char smem[TERMS == 3 ? 32768 : 24576];
    char* sAhi = smem;                 // [128][32] bf16, swizzled
    char* sWhi = smem + 8192;
    char* sWlo = smem + 16384;
    char* sAlo = (TERMS == 3) ? smem + 24576 : smem;  // unused if TERMS==2

    int tid = threadIdx.x;
    int l   = tid & 63;
    int w   = tid >> 6;
    int wr  = (w >> 1) * 64;           // wave row offset in tile
    int wc  = (w & 1) * 64;            // wave col offset in tile

    f32x4 acc[4][4];
#pragma unroll
    for (int mi = 0; mi < 4; ++mi)
#pragma unroll
        for (int ni = 0; ni < 4; ++ni) acc[mi][ni] = (f32x4){0.f, 0.f, 0.f, 0.f};

    int fr = l & 15;                   // frag row/col within 16
    int fk = (l >> 4) * 16;            // frag k-byte offset (8 bf16)

    for (int kt = 0; kt < K; kt += 32) {
        // ---- stage W hi/lo: 2 chunks of 16B per thread each ----
#pragma unroll
        for (int q = 0; q < 2; ++q) {
            int c = tid + 256 * q;
            int r = c >> 2, kc = c & 3;
            size_t gi = (size_t)(col0 + r) * K + kt + kc * 8;
            *(uint4*)(sWhi + swz(r, kc * 16)) = *(const uint4*)&Whi_g[gi];
            *(uint4*)(sWlo + swz(r, kc * 16)) = *(const uint4*)&Wlo_g[gi];
        }
        // ---- stage A ----
        if constexpr (std::is_same<TA, unsigned short>::value) {
#pragma unroll
            for (int q = 0; q < 2; ++q) {
                int c = tid + 256 * q;
                int r = c >> 2, kc = c & 3;
                *(uint4*)(sAhi + swz(r, kc * 16)) =
                    *(const uint4*)&A[(size_t)(row0 + r) * K + kt + kc * 8];
            }
        } else {
#pragma unroll
            for (int q = 0; q < 4; ++q) {
                int c = tid + 256 * q;
                int r = c >> 3, kc = c & 7;
                float4 f = *(const float4*)&A[(size_t)(row0 + r) * K + kt + kc * 4];
                ushort4 h, lo;
                h.x = f2bf(f.x); lo.x = f2bf(f.x - bf2f(h.x));
                h.y = f2bf(f.y); lo.y = f2bf(f.y - bf2f(h.y));
                h.z = f2bf(f.z); lo.z = f2bf(f.z - bf2f(h.z));
                h.w = f2bf(f.w); lo.w = f2bf(f.w - bf2f(h.w));
                *(ushort4*)(sAhi + swz(r, kc * 8)) = h;
                *(ushort4*)(sAlo + swz(r, kc * 8)) = lo;
            }
        }
        __syncthreads();

        // ---- fragment loads ----
        bf16x8 ah[4], al[4], bh[4], bl4[4];
#pragma unroll
        for (int mi = 0; mi < 4; ++mi) {
            int off = swz(wr + mi * 16 + fr, fk);
            ah[mi] = *(const bf16x8*)(sAhi + off);
            if (TERMS == 3) al[mi] = *(const bf16x8*)(sAlo + off);
        }
#pragma unroll
        for (int ni = 0; ni < 4; ++ni) {
            int off = swz(wc + ni * 16 + fr, fk);
            bh[ni]  = *(const bf16x8*)(sWhi + off);
            bl4[ni] = *(const bf16x8*)(sWlo + off);
        }
        // ---- MFMA ----
#pragma unroll
        for (int mi = 0; mi < 4; ++mi)
#pragma unroll
            for (int ni = 0; ni < 4; ++ni) {
                acc[mi][ni] = __builtin_amdgcn_mfma_f32_16x16x32_bf16(
                    ah[mi], bh[ni], acc[mi][ni], 0, 0, 0);
                acc[mi][ni] = __builtin_amdgcn_mfma_f32_16x16x32_bf16(
                    ah[mi], bl4[ni], acc[mi][ni], 0, 0, 0);
                if (TERMS == 3)
                    acc[mi][ni] = __builtin_amdgcn_mfma_f32_16x16x32_bf16(
                        al[mi], bh[ni], acc[mi][ni], 0, 0, 0);
            }
        __syncthreads();
    }

    // ---- epilogue: bias + bf16 store. D layout: col=lane&15, row=(lane>>4)*4+r ----
    int r4 = (l >> 4) * 4;
#pragma unroll
    for (int ni = 0; ni < 4; ++ni) {
        int col = col0 + wc + ni * 16 + fr;
        float bj = bias[col];
#pragma unroll
        for (int mi = 0; mi < 4; ++mi) {
            int row = row0 + wr + mi * 16 + r4;
            f32x4 v = acc[mi][ni];
#pragma unroll
            for (int r = 0; r < 4; ++r)
                out[(size_t)(row + r) * 1024 + col] = f2bf(v[r] + bj);
        }
    }
}

// ---------- LSTM recurrence (unchanged from R2) ----------
__global__ __launch_bounds__(512)
void lstm_rec(const unsigned short* __restrict__ xg,   // [ROWS][1024]
              const float* __restrict__ Whh,           // [2][512][128]
              const int* __restrict__ lens,            // chunk-offset
              unsigned short* __restrict__ hs,         // [ROWS][256] or null
              float* __restrict__ hTf, float* __restrict__ hTb,
              int bOff)
{
    int dir = blockIdx.x >> 7;
    int bl  = blockIdx.x & 127;
    int L   = lens[bl];
    int tid = threadIdx.x;
    int ks  = tid >> 7;
    int rr  = tid & 127;

    __shared__ float h_s[HD];
    __shared__ float gp[4][G4];

    float w[4][32];
#pragma unroll
    for (int g = 0; g < 4; ++g) {
        const float* wrow = Whh + ((size_t)dir * G4 + g * HD + rr) * HD + ks * 32;
#pragma unroll
        for (int k = 0; k < 32; k += 4) {
            float4 v = *(const float4*)(wrow + k);
            w[g][k] = v.x; w[g][k + 1] = v.y; w[g][k + 2] = v.z; w[g][k + 3] = v.w;
        }
    }

    if (tid < HD) h_s[tid] = 0.0f;
    float c = 0.0f, hkeep = 0.0f;
    __syncthreads();

    const unsigned short* xgb = xg + (size_t)bl * T_LEN * 1024 + (size_t)dir * G4;
    int tt   = dir ? (L - 1) : 0;
    int step = dir ? -1 : 1;

    float xv0 = 0.f, xv1 = 0.f, xv2 = 0.f, xv3 = 0.f;
    if (tid < HD) {
        const unsigned short* p = xgb + (size_t)tt * 1024;
        xv0 = bf2f(p[tid]);       xv1 = bf2f(p[tid + 128]);
        xv2 = bf2f(p[tid + 256]); xv3 = bf2f(p[tid + 384]);
    }

    for (int t = 0; t < L; ++t) {
        float a0 = 0.f, a1 = 0.f, a2 = 0.f, a3 = 0.f;
        const float* hq = &h_s[ks * 32];
#pragma unroll
        for (int k = 0; k < 32; k += 4) {
            float4 h4 = *(const float4*)(hq + k);
            a0 += w[0][k] * h4.x + w[0][k+1] * h4.y + w[0][k+2] * h4.z + w[0][k+3] * h4.w;
            a1 += w[1][k] * h4.x + w[1][k+1] * h4.y + w[1][k+2] * h4.z + w[1][k+3] * h4.w;
            a2 += w[2][k] * h4.x + w[2][k+1] * h4.y + w[2][k+2] * h4.z + w[2][k+3] * h4.w;
            a3 += w[3][k] * h4.x + w[3][k+1] * h4.y + w[3][k+2] * h4.z + w[3][k+3] * h4.w;
        }
        gp[ks][rr]       = a0;
        gp[ks][rr + 128] = a1;
        gp[ks][rr + 256] = a2;
        gp[ks][rr + 384] = a3;
        LDS_BARRIER();

        if (tid < HD) {
            float gi = xv0 + ((gp[0][tid]       + gp[1][tid])       + (gp[2][tid]       + gp[3][tid]));
            float gf = xv1 + ((gp[0][tid + 128] + gp[1][tid + 128]) + (gp[2][tid + 128] + gp[3][tid + 128]));
            float gg = xv2 + ((gp[0][tid + 256] + gp[1][tid + 256]) + (gp[2][tid + 256] + gp[3][tid + 256]));
            float go = xv3 + ((gp[0][tid + 384] + gp[1][tid + 384]) + (gp[2][tid + 384] + gp[3][tid + 384]));

            int ttn = (t + 1 < L) ? (tt + step) : tt;
            const unsigned short* p = xgb + (size_t)ttn * 1024;
            xv0 = bf2f(p[tid]);       xv1 = bf2f(p[tid + 128]);
            xv2 = bf2f(p[tid + 256]); xv3 = bf2f(p[tid + 384]);

            float ig = sigf(gi);
            float fg = sigf(gf);
            float G  = tanh_f(gg);
            float og = sigf(go);
            c = fg * c + ig * G;
            float hn = og * tanh_f(c);
            h_s[tid] = hn;
            hkeep = hn;
            if (hs) hs[(size_t)(bl * T_LEN + tt) * 256 + dir * HD + tid] = f2bf(hn);
        }
        LDS_BARRIER();
        tt += step;
    }
    if (hTf && tid < HD) {
        (dir ? hTb : hTf)[(size_t)(bOff + bl) * HD + tid] = hkeep;
    }
}

// ---------- final FC + log_softmax ----------
__global__ __launch_bounds__(256)
void fc_lsm(const float* __restrict__ hTf, const float* __restrict__ hTb,
            const float* __restrict__ Wfc, const float* __restrict__ bfc,
            float* __restrict__ out)
{
    int b = threadIdx.x;
    const float* hb = hTb + (size_t)b * HD;
    const float* hf = hTf + (size_t)b * HD;
    float l[NC];
#pragma unroll
    for (int cc = 0; cc < NC; ++cc) {
        const float* wr = Wfc + cc * 256;
        float acc = bfc[cc];
        for (int k = 0; k < HD; k += 4) {
            acc += hb[k] * wr[k] + hb[k + 1] * wr[k + 1]
                 + hb[k + 2] * wr[k + 2] + hb[k + 3] * wr[k + 3];
            acc += hf[k] * wr[128 + k] + hf[k + 1] * wr[128 + k + 1]
                 + hf[k + 2] * wr[128 + k + 2] + hf[k + 3] * wr[128 + k + 3];
        }
        l[cc] = acc;
    }
    float m = l[0];
#pragma unroll
    for (int cc = 1; cc < NC; ++cc) m = fmaxf(m, l[cc]);
    float s = 0.0f;
#pragma unroll
    for (int cc = 0; cc < NC; ++cc) s += __expf(l[cc] - m);
    float lg = m + logf(s);
#pragma unroll
    for (int cc = 0; cc < NC; ++cc) out[(size_t)b * NC + cc] = l[cc] - lg;
}

extern "C" void kernel_launch(void* const* d_in, const int* in_sizes, int n_in,
                              void* d_out, int out_size, void* d_ws, size_t ws_size,
                              hipStream_t stream)
{
    const float* X    = (const float*)d_in[0];
    const int*   len  = (const int*)d_in[1];
    const float* Wih0 = (const float*)d_in[2];   // (2,512,64)  -> (1024,64)
    const float* Whh0 = (const float*)d_in[3];   // (2,512,128)
    const float* b0   = (const float*)d_in[4];   // (2,512) -> (1024)
    const float* Wih1 = (const float*)d_in[5];   // (2,512,256) -> (1024,256)
    const float* Whh1 = (const float*)d_in[6];
    const float* b1   = (const float*)d_in[7];
    const float* Wfc  = (const float*)d_in[8];   // (12,256)
    const float* bfc  = (const float*)d_in[9];   // (12)
    float* out = (float*)d_out;

    char* ws = (char*)d_ws;
    size_t off = 0;
    unsigned short* xg = (unsigned short*)(ws + off); off += (size_t)ROWS * 1024 * 2;
    unsigned short* h1 = (unsigned short*)(ws + off); off += (size_t)ROWS * 256 * 2;
    float* hTf = (float*)(ws + off); off += (size_t)B_ALL * HD * 4;
    float* hTb = (float*)(ws + off); off += (size_t)B_ALL * HD * 4;
    unsigned short* W0hi = (unsigned short*)(ws + off); off += 1024 * 64 * 2;
    unsigned short* W0lo = (unsigned short*)(ws + off); off += 1024 * 64 * 2;
    unsigned short* W1hi = (unsigned short*)(ws + off); off += 1024 * 256 * 2;
    unsigned short* W1lo = (unsigned short*)(ws + off); off += 1024 * 256 * 2;

    // one-time W splits (cheap)
    split_w<<<(1024 * 64 + 255) / 256, 256, 0, stream>>>(Wih0, W0hi, W0lo, 1024 * 64);
    split_w<<<(1024 * 256 + 255) / 256, 256, 0, stream>>>(Wih1, W1hi, W1lo, 1024 * 256);

    for (int ch = 0; ch < 2; ++ch) {
        const int* lc = len + ch * BCH;
        const float* Xc = X + (size_t)ch * BCH * T_LEN * D_INP;

        gates_gemm_mfma<3, float><<<dim3(ROWS / 128, 8), 256, 0, stream>>>(
            Xc, W0hi, W0lo, b0, lc, xg, D_INP);
        lstm_rec<<<2 * BCH, 512, 0, stream>>>(xg, Whh0, lc, h1, nullptr, nullptr, 0);
        gates_gemm_mfma<2, unsigned short><<<dim3(ROWS / 128, 8), 256, 0, stream>>>(
            h1, W1hi, W1lo, b1, lc, xg, 2 * HD);
        lstm_rec<<<2 * BCH, 512, 0, stream>>>(xg, Whh1, lc, nullptr, hTf, hTb, ch * BCH);
    }
    fc_lsm<<<1, 256, 0, stream>>>(hTf, hTb, Wfc, bfc, out);
}